// Round 5
// baseline (647.705 us; speedup 1.0000x reference)
//
#include <hip/hip_runtime.h>
#include <hip/hip_bf16.h>

using bf16 = __hip_bfloat16;
typedef __attribute__((ext_vector_type(8))) short short8;   // 8 bf16 = 4 VGPRs (MFMA A/B frag)
typedef __attribute__((ext_vector_type(4))) float f32x4;    // MFMA C/D frag

static __device__ __forceinline__ float b2f(bf16 x) { return __bfloat162float(x); }

static __device__ __forceinline__ unsigned int packbf2(float a, float b) {
    bf16 x = __float2bfloat16(a), y = __float2bfloat16(b);
    unsigned short ux = *(unsigned short*)&x, uy = *(unsigned short*)&y;
    return (unsigned int)ux | ((unsigned int)uy << 16);
}

// ---------------- dtype auto-detection (deterministic) -----------------------
// flags[0]=1 -> float inputs are fp32 (else bf16). flags[1]=1 -> edges int64.
__global__ void det_kernel(const unsigned short* __restrict__ xh,
                           const int* __restrict__ ei, int* __restrict__ flags) {
    __shared__ int s_exp, s_nz;
    if (threadIdx.x == 0) { s_exp = 0; s_nz = 0; }
    __syncthreads();
    if (threadIdx.x < 256) {
        unsigned short h = xh[threadIdx.x];
        int ef = (h >> 7) & 0xFF;
        if (ef < 100 || ef > 140) atomicAdd(&s_exp, 1);
    }
    for (int i = 1 + 2 * threadIdx.x; i < 4096; i += 2 * blockDim.x)
        if (ei[i] != 0) atomicAdd(&s_nz, 1);
    __syncthreads();
    if (threadIdx.x == 0) {
        flags[0] = (s_exp > 16) ? 1 : 0;
        flags[1] = (s_nz == 0) ? 1 : 0;
    }
}

// ---------------- canonicalizers --------------------------------------------
struct CanonWB { const void* src[8]; float* dst[8]; int n[8]; };

__global__ void canon_w_batch(CanonWB cb, const int* __restrict__ flags) {
    int j = blockIdx.x;
    const void* src = cb.src[j];
    float* dst = cb.dst[j];
    int n = cb.n[j];
    int m32 = flags[0];
    for (int i = threadIdx.x; i < n; i += blockDim.x)
        dst[i] = m32 ? ((const float*)src)[i] : b2f(((const bf16*)src)[i]);
}

// 8 elems / thread (n % 8 == 0): fp32 path reads 2x float4, bf16 path copies uint4.
__global__ void canon_x8(const void* __restrict__ src, const int* __restrict__ flags,
                         bf16* __restrict__ dst, int n8) {
    int i = blockIdx.x * blockDim.x + threadIdx.x;
    if (i >= n8) return;
    if (flags[0]) {
        const float4* s = (const float4*)src;
        float4 x = s[2 * i], y = s[2 * i + 1];
        uint4 r;
        r.x = packbf2(x.x, x.y); r.y = packbf2(x.z, x.w);
        r.z = packbf2(y.x, y.y); r.w = packbf2(y.z, y.w);
        ((uint4*)dst)[i] = r;
    } else {
        ((uint4*)dst)[i] = ((const uint4*)src)[i];
    }
}

// canon_edges fused with degree histogram (counts must be pre-zeroed)
__global__ void canon_edges_hist(const int* __restrict__ ei, const int* __restrict__ flags,
                                 int* __restrict__ srcd, int* __restrict__ dstd,
                                 int* __restrict__ counts, int E) {
    int e = blockIdx.x * blockDim.x + threadIdx.x;
    if (e >= E) return;
    int s, d;
    if (flags[1]) { s = ei[2 * e]; d = ei[2 * E + 2 * e]; }
    else          { s = ei[e];     d = ei[E + e]; }
    srcd[e] = s; dstd[e] = d;
    atomicAdd(&counts[d], 1);
}

// Split fp32 weights W[K,F] into transposed bf16 hi/lo pair Wt[F,K].
struct PrepB { const void* src[6]; int lgK[6]; int F[6]; int off[6]; int end[6]; };

__global__ void prep_wt_batch(PrepB pb, const int* __restrict__ flags,
                              bf16* __restrict__ Wth, bf16* __restrict__ Wtl, int total) {
    int g = blockIdx.x * blockDim.x + threadIdx.x;
    if (g >= total) return;
    int j = 0;
#pragma unroll
    for (int t = 0; t < 6; ++t) if (g >= pb.end[t]) j = t + 1;
    const void* src = pb.src[j];
    int lgK = pb.lgK[j], F = pb.F[j];
    int local = g - pb.off[j];
    int f = local >> lgK, k = local & ((1 << lgK) - 1);
    float v = flags[0] ? ((const float*)src)[(size_t)k * F + f]
                       : b2f(((const bf16*)src)[(size_t)k * F + f]);
    bf16 hi = __float2bfloat16(v);
    float lo = v - b2f(hi);
    Wth[g] = hi;
    Wtl[g] = __float2bfloat16(lo);
}

// ---------------- CSR build -------------------------------------------------
__global__ void scan_part1(const int* __restrict__ counts, int* __restrict__ blockSums, int N) {
    __shared__ int red[256];
    int i = blockIdx.x * 256 + threadIdx.x;
    red[threadIdx.x] = (i < N) ? counts[i] : 0;
    __syncthreads();
    for (int off = 128; off > 0; off >>= 1) {
        if (threadIdx.x < off) red[threadIdx.x] += red[threadIdx.x + off];
        __syncthreads();
    }
    if (threadIdx.x == 0) blockSums[blockIdx.x] = red[0];
}

__global__ void scan_part2(const int* __restrict__ blockSums, int* __restrict__ blockOff,
                           int* __restrict__ rowPtrN, int G) {
    __shared__ int s[256];
    int t = threadIdx.x;
    s[t] = (t < G) ? blockSums[t] : 0;
    __syncthreads();
    for (int off = 1; off < 256; off <<= 1) {
        int v = (t >= off) ? s[t - off] : 0;
        __syncthreads();
        s[t] += v;
        __syncthreads();
    }
    if (t < G) blockOff[t] = (t > 0) ? s[t - 1] : 0;
    if (t == 255) *rowPtrN = s[255];
}

__global__ void scan_part3(const int* __restrict__ counts, const int* __restrict__ blockOff,
                           int* __restrict__ rowPtr, int* __restrict__ cursor,
                           float* __restrict__ dinv, int N) {
    __shared__ int s[256];
    int t = threadIdx.x;
    int i = blockIdx.x * 256 + t;
    int c = (i < N) ? counts[i] : 0;
    s[t] = c;
    __syncthreads();
    for (int off = 1; off < 256; off <<= 1) {
        int v = (t >= off) ? s[t - off] : 0;
        __syncthreads();
        s[t] += v;
        __syncthreads();
    }
    if (i < N) {
        int o = blockOff[blockIdx.x] + s[t] - c;     // exclusive prefix
        rowPtr[i] = o;
        cursor[i] = o;
        dinv[i] = rsqrtf((float)c + 1.0f);
    }
}

__global__ void scatter_kernel(const int* __restrict__ srcv, const int* __restrict__ dstv,
                               int* __restrict__ cursor, int* __restrict__ sortedSrc, int E) {
    int e = blockIdx.x * blockDim.x + threadIdx.x;
    if (e >= E) return;
    int p = atomicAdd(&cursor[dstv[e]], 1);
    sortedSrc[p] = srcv[e];
}

// ---------------- MFMA GEMM -------------------------------------------------
// C[N,F] = A[N,K](bf16) @ (Wth+Wtl)[K,F]. Epilogue: *dinv?[row] + bias?[col]; relu?;
// optional out2 = bf16(v * dinv2[row]). 64x64 tile, K chunks of 64, XOR-swizzled LDS.
template <int K>
__global__ __launch_bounds__(256)
void mfma_gemm(const bf16* __restrict__ A,
               const bf16* __restrict__ Wth, const bf16* __restrict__ Wtl,
               const float* __restrict__ bias, const float* __restrict__ dinv,
               void* __restrict__ out, const int* __restrict__ flags,
               int outmode, int relu, bf16* __restrict__ out2,
               const float* __restrict__ dinv2, int F, int N) {
    __shared__ uint4 lds4[1536];               // 24 KB = 1536 x 16B granules
    char* lds = (char*)lds4;
    const int tid = threadIdx.x;
    const int w = tid >> 6, lane = tid & 63;
    const int rowBase = blockIdx.y * 64;
    const int colBase = blockIdx.x * 64;

    f32x4 zero = {0.f, 0.f, 0.f, 0.f};
    f32x4 acc[4];
#pragma unroll
    for (int n = 0; n < 4; ++n) acc[n] = zero;

    const int arow = (w << 4) + (lane & 15);
    const int aswz = arow & 7;
    const int colL = lane & 15;

    for (int kc = 0; kc < K; kc += 64) {
#pragma unroll
        for (int i = 0; i < 6; ++i) {
            const int g = i * 256 + tid;
            char* dst = lds + ((i * 256 + (w << 6)) << 4);
            const bf16* src;
            if (g < 512) {
                int r = g >> 3, c = g & 7;
                int gr = rowBase + r; if (gr >= N) gr = N - 1;
                src = A + (size_t)gr * K + kc + ((c ^ (r & 7)) << 3);
            } else if (g < 1024) {
                int h = g - 512; int cl = h >> 3, c = h & 7;
                src = Wth + (size_t)(colBase + cl) * K + kc + ((c ^ (cl & 7)) << 3);
            } else {
                int h = g - 1024; int cl = h >> 3, c = h & 7;
                src = Wtl + (size_t)(colBase + cl) * K + kc + ((c ^ (cl & 7)) << 3);
            }
            __builtin_amdgcn_global_load_lds(
                (const __attribute__((address_space(1))) void*)src,
                (__attribute__((address_space(3))) void*)dst, 16, 0, 0);
        }
        __syncthreads();

        const char* aB = lds;
        const char* hB = lds + 8192;
        const char* lB = lds + 16384;
#pragma unroll
        for (int ks = 0; ks < 2; ++ks) {
            const int c = (ks << 2) + (lane >> 4);
            short8 a = *(const short8*)(aB + (((arow << 3) + (c ^ aswz)) << 4));
#pragma unroll
            for (int n = 0; n < 4; ++n) {
                const int col = (n << 4) + colL;
                const int s = ((col << 3) + (c ^ (col & 7))) << 4;
                short8 bh = *(const short8*)(hB + s);
                short8 bl = *(const short8*)(lB + s);
                acc[n] = __builtin_amdgcn_mfma_f32_16x16x32_bf16(a, bh, acc[n], 0, 0, 0);
                acc[n] = __builtin_amdgcn_mfma_f32_16x16x32_bf16(a, bl, acc[n], 0, 0, 0);
            }
        }
        __syncthreads();
    }

    // C/D layout: col = lane&15, row = (lane>>4)*4 + reg (m89/m91)
    const int m32 = outmode ? flags[0] : 0;
    const int r0 = rowBase + (w << 4) + ((lane >> 4) << 2);
#pragma unroll
    for (int n = 0; n < 4; ++n) {
        const int col = colBase + (n << 4) + colL;
        const float bv = bias ? bias[col] : 0.0f;
#pragma unroll
        for (int r = 0; r < 4; ++r) {
            const int row = r0 + r;
            if (row < N) {
                float v = acc[n][r];
                if (dinv) v *= dinv[row];
                v += bv;
                if (relu) v = fmaxf(v, 0.0f);
                size_t o = (size_t)row * F + col;
                if (m32) ((float*)out)[o] = v;
                else     ((bf16*)out)[o] = __float2bfloat16(v);
                if (out2) out2[o] = __float2bfloat16(v * dinv2[row]);
            }
        }
    }
}

// ---------------- gather: 64-col pass, 2 rows per wave-instruction ----------
// out[node, colOff..colOff+63] = act(dinv[node]*(Σ_in H'[s] + H'[node]) + bias).
// Lanes 0-31 process even entries, 32-63 odd (per-lane shfl src); each lane
// covers 2 columns via a 4B load. Cross-half combine: one shfl_xor(32).
// F=128 layers run 2 passes (colOff 0/64) -> per-pass working set halves (L2).
__global__ void gather2(const bf16* __restrict__ Hs, const int* __restrict__ rowPtr,
                        const int* __restrict__ sortedSrc, const float* __restrict__ dinv,
                        const float* __restrict__ bias, bf16* __restrict__ out,
                        int relu, int N, int stride, int colOff) {
    int node = blockIdx.x * 4 + (threadIdx.x >> 6);
    int lane = threadIdx.x & 63;
    if (node >= N) return;
    const int half = lane >> 5;
    const int cl = lane & 31;                    // column pair: 2*cl, 2*cl+1
    const size_t cbase = (size_t)colOff + 2 * cl;
    float a0 = 0.0f, a1 = 0.0f;
    const int beg = rowPtr[node], end = rowPtr[node + 1];
    const int total = end - beg + 1;             // entry 0 = self
    for (int b0 = 0; b0 < total; b0 += 64) {
        int idx = b0 + lane;
        int myS = 0;
        if (idx == 0) myS = node;
        else if (idx < total) myS = sortedSrc[beg + idx - 1];
        int m = total - b0; if (m > 64) m = 64;
        int j = 0;
        for (; j + 3 < m; j += 4) {              // 4 entries in flight
            int s0 = __shfl(myS, j + half);
            int s1 = __shfl(myS, j + 2 + half);
            unsigned int u0 = *(const unsigned int*)(Hs + (size_t)s0 * stride + cbase);
            unsigned int u1 = *(const unsigned int*)(Hs + (size_t)s1 * stride + cbase);
            union { unsigned int i; float f; } lo, hi;
            lo.i = u0 << 16; hi.i = u0 & 0xffff0000u; a0 += lo.f; a1 += hi.f;
            lo.i = u1 << 16; hi.i = u1 & 0xffff0000u; a0 += lo.f; a1 += hi.f;
        }
        for (; j < m; j += 2) {
            int idx2 = j + half;
            int s0 = __shfl(myS, idx2);
            if (idx2 < m) {
                unsigned int u0 = *(const unsigned int*)(Hs + (size_t)s0 * stride + cbase);
                union { unsigned int i; float f; } lo, hi;
                lo.i = u0 << 16; hi.i = u0 & 0xffff0000u; a0 += lo.f; a1 += hi.f;
            }
        }
    }
    a0 += __shfl_xor(a0, 32);
    a1 += __shfl_xor(a1, 32);
    if (half == 0) {
        const float di = dinv[node];
        float v0 = a0 * di, v1 = a1 * di;
        if (bias) { v0 += bias[cbase]; v1 += bias[cbase + 1]; }
        if (relu) { v0 = fmaxf(v0, 0.0f); v1 = fmaxf(v1, 0.0f); }
        *(unsigned int*)(out + (size_t)node * stride + cbase) = packbf2(v0, v1);
    }
}

// ---------------- link predictor --------------------------------------------
__global__ void link_pre(const bf16* __restrict__ Z, const float* __restrict__ lw,
                         float* __restrict__ ab, int N) {
    int node = blockIdx.x * (blockDim.x >> 6) + (threadIdx.x >> 6);
    int lane = threadIdx.x & 63;
    if (node >= N) return;
    float zv = b2f(Z[(size_t)node * 64 + lane]);
    float va = zv * lw[lane];
    float vb = zv * lw[64 + lane];
#pragma unroll
    for (int off = 32; off > 0; off >>= 1) {
        va += __shfl_down(va, off);
        vb += __shfl_down(vb, off);
    }
    if (lane == 0) { ab[2 * node] = va; ab[2 * node + 1] = vb; }
}

__global__ void link_edge(const float* __restrict__ ab, const int* __restrict__ srcv,
                          const int* __restrict__ dstv, const float* __restrict__ lb,
                          void* __restrict__ out, const int* __restrict__ flags,
                          size_t outOff, int E) {
    int e = blockIdx.x * blockDim.x + threadIdx.x;
    if (e >= E) return;
    float v = ab[2 * srcv[e]] + ab[2 * dstv[e] + 1] + lb[0];
    float sv = 1.0f / (1.0f + expf(-v));
    if (flags[0]) ((float*)out)[outOff + e] = sv;
    else          ((bf16*)out)[outOff + e] = __float2bfloat16(sv);
}

// ---------------- launch ----------------------------------------------------
extern "C" void kernel_launch(void* const* d_in, const int* in_sizes, int n_in,
                              void* d_out, int out_size, void* d_ws, size_t ws_size,
                              hipStream_t stream) {
    const int N = in_sizes[0] / 128;   // 50000
    const int E = in_sizes[1] / 2;     // 800000

    char* base = (char*)d_ws;
    size_t off = 0;
    auto alloc = [&](size_t bytes) { char* p = base + off; off = (off + bytes + 255) & ~(size_t)255; return p; };
    int*   flags  = (int*)  alloc(256);
    float* dinv   = (float*)alloc((size_t)N * 4);
    float* Wc     = (float*)alloc((size_t)210689 * 4);
    int*   counts = (int*)  alloc((size_t)N * 4);
    int*   rowPtr = (int*)  alloc(((size_t)N + 1) * 4);
    int*   cursor = (int*)  alloc((size_t)N * 4);
    int*   sortedSrc = (int*)alloc((size_t)E * 4);
    int*   srcd   = (int*)  alloc((size_t)E * 4);
    int*   dstd   = (int*)  alloc((size_t)E * 4);
    bf16*  Hs     = (bf16*) alloc((size_t)N * 256 * 2);  // scaled GEMM out / agg buffer
    bf16*  P0     = (bf16*) alloc((size_t)N * 256 * 2);  // layer output
    bf16*  z      = (bf16*) alloc((size_t)N * 64 * 2);
    bf16*  zs     = (bf16*) alloc((size_t)N * 64 * 2);   // dinv ⊙ z
    bf16*  Wth    = (bf16*) alloc((size_t)208896 * 2);
    bf16*  Wtl    = (bf16*) alloc((size_t)208896 * 2);
    float* ab     = (float*)alloc((size_t)N * 2 * 4);
    int*   blockSums = (int*)alloc(256 * 4);
    int*   blockOff  = (int*)alloc(256 * 4);

    const int W_EB1 = 16384, W_EB2 = 24704, W_EFB = 28864, W_DB1 = 45312,
              W_DB2 = 78336, W_DFB = 209536, W_LW = 210560, W_LB = 210688;
    const int T_EW1 = 0, T_EW2 = 16384, T_EFW = 24576, T_DW1 = 28672,
              T_DW2 = 45056, T_DFW = 77824;

    det_kernel<<<1, 256, 0, stream>>>((const unsigned short*)d_in[0], (const int*)d_in[1], flags);

    // CSR + dinv (hist fused into edge canon; multi-block scan)
    hipMemsetAsync(counts, 0, (size_t)N * 4, stream);
    canon_edges_hist<<<(E + 255) / 256, 256, 0, stream>>>((const int*)d_in[1], flags,
                                                          srcd, dstd, counts, E);
    const int gScan = (N + 255) / 256;
    scan_part1<<<gScan, 256, 0, stream>>>(counts, blockSums, N);
    scan_part2<<<1, 256, 0, stream>>>(blockSums, blockOff, rowPtr + N, gScan);
    scan_part3<<<gScan, 256, 0, stream>>>(counts, blockOff, rowPtr, cursor, dinv, N);
    scatter_kernel<<<(E + 255) / 256, 256, 0, stream>>>(srcd, dstd, cursor, sortedSrc, E);

    {   // biases / link weights -> canonical fp32 (1 launch)
        CanonWB cb;
        const int idx[8]  = {3, 5, 7, 9, 11, 13, 14, 15};
        const int woff[8] = {W_EB1, W_EB2, W_EFB, W_DB1, W_DB2, W_DFB, W_LW, W_LB};
        for (int j = 0; j < 8; ++j) {
            cb.src[j] = d_in[idx[j]];
            cb.dst[j] = Wc + woff[j];
            cb.n[j] = in_sizes[idx[j]];
        }
        canon_w_batch<<<8, 256, 0, stream>>>(cb, flags);
    }
    {   // GEMM weights -> transposed bf16 hi/lo split (1 launch)
        PrepB pb;
        const int idx[6]  = {2, 4, 6, 8, 10, 12};
        const int toff[6] = {T_EW1, T_EW2, T_EFW, T_DW1, T_DW2, T_DFW};
        const int lgk[6]  = {7, 7, 6, 6, 8, 7};
        const int ff[6]   = {128, 64, 64, 256, 128, 1024};
        int total = 0;
        for (int j = 0; j < 6; ++j) {
            pb.src[j] = d_in[idx[j]];
            pb.lgK[j] = lgk[j];
            pb.F[j] = ff[j];
            pb.off[j] = toff[j];
            pb.end[j] = toff[j] + (ff[j] << lgk[j]);
            total = pb.end[j];
        }
        prep_wt_batch<<<(total + 255) / 256, 256, 0, stream>>>(pb, flags, Wth, Wtl, total);
    }
    canon_x8<<<(N * 16 + 255) / 256, 256, 0, stream>>>(d_in[0], flags, P0, N * 16);

    const int gRB = (N + 63) / 64;
    const int gG = (N + 3) / 4;

    // Encoder GCN1: 128 -> 128 (H' = dinv * X@W); gather in 2 column passes, ReLU
    mfma_gemm<128><<<dim3(2, gRB), 256, 0, stream>>>(P0, Wth + T_EW1, Wtl + T_EW1,
                                                     nullptr, dinv, Hs, flags, 0, 0,
                                                     nullptr, nullptr, 128, N);
    gather2<<<gG, 256, 0, stream>>>(Hs, rowPtr, sortedSrc, dinv, Wc + W_EB1, P0, 1, N, 128, 0);
    gather2<<<gG, 256, 0, stream>>>(Hs, rowPtr, sortedSrc, dinv, Wc + W_EB1, P0, 1, N, 128, 64);

    // Encoder GCN2: 128 -> 64
    mfma_gemm<128><<<dim3(1, gRB), 256, 0, stream>>>(P0, Wth + T_EW2, Wtl + T_EW2,
                                                     nullptr, dinv, Hs, flags, 0, 0,
                                                     nullptr, nullptr, 64, N);
    gather2<<<gG, 256, 0, stream>>>(Hs, rowPtr, sortedSrc, dinv, Wc + W_EB2, P0, 0, N, 64, 0);

    // Latent fc: z = P0 @ efw + efb; zs = dinv ⊙ z (free in epilogue)
    mfma_gemm<64><<<dim3(1, gRB), 256, 0, stream>>>(P0, Wth + T_EFW, Wtl + T_EFW,
                                                    Wc + W_EFB, nullptr, z, flags, 0, 0,
                                                    zs, dinv, 64, N);

    // link partials (needs z only)
    link_pre<<<gG, 256, 0, stream>>>(z, Wc + W_LW, ab, N);

    // Decoder GCN1 (aggregate-before-transform on F=64), then GEMM 64->256 +bias+ReLU
    gather2<<<gG, 256, 0, stream>>>(zs, rowPtr, sortedSrc, dinv, nullptr, Hs, 0, N, 64, 0);
    mfma_gemm<64><<<dim3(4, gRB), 256, 0, stream>>>(Hs, Wth + T_DW1, Wtl + T_DW1,
                                                    Wc + W_DB1, nullptr, P0, flags, 0, 1,
                                                    nullptr, nullptr, 256, N);

    // Decoder GCN2: 256 -> 128; gather in 2 column passes
    mfma_gemm<256><<<dim3(2, gRB), 256, 0, stream>>>(P0, Wth + T_DW2, Wtl + T_DW2,
                                                     nullptr, dinv, Hs, flags, 0, 0,
                                                     nullptr, nullptr, 128, N);
    gather2<<<gG, 256, 0, stream>>>(Hs, rowPtr, sortedSrc, dinv, Wc + W_DB2, P0, 0, N, 128, 0);
    gather2<<<gG, 256, 0, stream>>>(Hs, rowPtr, sortedSrc, dinv, Wc + W_DB2, P0, 0, N, 128, 64);

    // x_hat = P0 @ dfw + dfb (128 -> 1024) into d_out, detected dtype
    mfma_gemm<128><<<dim3(16, gRB), 256, 0, stream>>>(P0, Wth + T_DFW, Wtl + T_DFW,
                                                      Wc + W_DFB, nullptr, d_out, flags, 1, 0,
                                                      nullptr, nullptr, 1024, N);

    // edge_probs
    link_edge<<<(E + 255) / 256, 256, 0, stream>>>(ab, srcd, dstd, Wc + W_LB,
                                                   d_out, flags, (size_t)N * 1024, E);
}

// Round 6
// 619.555 us; speedup vs baseline: 1.0454x; 1.0454x over previous
//
#include <hip/hip_runtime.h>
#include <hip/hip_bf16.h>

using bf16 = __hip_bfloat16;
typedef __attribute__((ext_vector_type(8))) short short8;   // 8 bf16 = 4 VGPRs (MFMA A/B frag)
typedef __attribute__((ext_vector_type(4))) float f32x4;    // MFMA C/D frag

static __device__ __forceinline__ float b2f(bf16 x) { return __bfloat162float(x); }

static __device__ __forceinline__ unsigned int packbf2(float a, float b) {
    bf16 x = __float2bfloat16(a), y = __float2bfloat16(b);
    unsigned short ux = *(unsigned short*)&x, uy = *(unsigned short*)&y;
    return (unsigned int)ux | ((unsigned int)uy << 16);
}

// ---------------- dtype auto-detection (deterministic) -----------------------
// flags[0]=1 -> float inputs are fp32 (else bf16). flags[1]=1 -> edges int64.
__global__ void det_kernel(const unsigned short* __restrict__ xh,
                           const int* __restrict__ ei, int* __restrict__ flags) {
    __shared__ int s_exp, s_nz;
    if (threadIdx.x == 0) { s_exp = 0; s_nz = 0; }
    __syncthreads();
    if (threadIdx.x < 256) {
        unsigned short h = xh[threadIdx.x];
        int ef = (h >> 7) & 0xFF;
        if (ef < 100 || ef > 140) atomicAdd(&s_exp, 1);
    }
    for (int i = 1 + 2 * threadIdx.x; i < 4096; i += 2 * blockDim.x)
        if (ei[i] != 0) atomicAdd(&s_nz, 1);
    __syncthreads();
    if (threadIdx.x == 0) {
        flags[0] = (s_exp > 16) ? 1 : 0;
        flags[1] = (s_nz == 0) ? 1 : 0;
    }
}

// ---------------- canonicalizers --------------------------------------------
struct CanonWB { const void* src[8]; float* dst[8]; int n[8]; };

__global__ void canon_w_batch(CanonWB cb, const int* __restrict__ flags) {
    int j = blockIdx.x;
    const void* src = cb.src[j];
    float* dst = cb.dst[j];
    int n = cb.n[j];
    int m32 = flags[0];
    for (int i = threadIdx.x; i < n; i += blockDim.x)
        dst[i] = m32 ? ((const float*)src)[i] : b2f(((const bf16*)src)[i]);
}

// 8 elems / thread (n % 8 == 0): fp32 path reads 2x float4, bf16 path copies uint4.
__global__ void canon_x8(const void* __restrict__ src, const int* __restrict__ flags,
                         bf16* __restrict__ dst, int n8) {
    int i = blockIdx.x * blockDim.x + threadIdx.x;
    if (i >= n8) return;
    if (flags[0]) {
        const float4* s = (const float4*)src;
        float4 x = s[2 * i], y = s[2 * i + 1];
        uint4 r;
        r.x = packbf2(x.x, x.y); r.y = packbf2(x.z, x.w);
        r.z = packbf2(y.x, y.y); r.w = packbf2(y.z, y.w);
        ((uint4*)dst)[i] = r;
    } else {
        ((uint4*)dst)[i] = ((const uint4*)src)[i];
    }
}

// canon_edges fused with degree histogram (counts must be pre-zeroed)
__global__ void canon_edges_hist(const int* __restrict__ ei, const int* __restrict__ flags,
                                 int* __restrict__ srcd, int* __restrict__ dstd,
                                 int* __restrict__ counts, int E) {
    int e = blockIdx.x * blockDim.x + threadIdx.x;
    if (e >= E) return;
    int s, d;
    if (flags[1]) { s = ei[2 * e]; d = ei[2 * E + 2 * e]; }
    else          { s = ei[e];     d = ei[E + e]; }
    srcd[e] = s; dstd[e] = d;
    atomicAdd(&counts[d], 1);
}

// Split fp32 weights W[K,F] into transposed bf16 hi/lo pair Wt[F,K].
struct PrepB { const void* src[6]; int lgK[6]; int F[6]; int off[6]; int end[6]; };

__global__ void prep_wt_batch(PrepB pb, const int* __restrict__ flags,
                              bf16* __restrict__ Wth, bf16* __restrict__ Wtl, int total) {
    int g = blockIdx.x * blockDim.x + threadIdx.x;
    if (g >= total) return;
    int j = 0;
#pragma unroll
    for (int t = 0; t < 6; ++t) if (g >= pb.end[t]) j = t + 1;
    const void* src = pb.src[j];
    int lgK = pb.lgK[j], F = pb.F[j];
    int local = g - pb.off[j];
    int f = local >> lgK, k = local & ((1 << lgK) - 1);
    float v = flags[0] ? ((const float*)src)[(size_t)k * F + f]
                       : b2f(((const bf16*)src)[(size_t)k * F + f]);
    bf16 hi = __float2bfloat16(v);
    float lo = v - b2f(hi);
    Wth[g] = hi;
    Wtl[g] = __float2bfloat16(lo);
}

// ---------------- CSR build -------------------------------------------------
__global__ void scan_part1(const int* __restrict__ counts, int* __restrict__ blockSums, int N) {
    __shared__ int red[256];
    int i = blockIdx.x * 256 + threadIdx.x;
    red[threadIdx.x] = (i < N) ? counts[i] : 0;
    __syncthreads();
    for (int off = 128; off > 0; off >>= 1) {
        if (threadIdx.x < off) red[threadIdx.x] += red[threadIdx.x + off];
        __syncthreads();
    }
    if (threadIdx.x == 0) blockSums[blockIdx.x] = red[0];
}

__global__ void scan_part2(const int* __restrict__ blockSums, int* __restrict__ blockOff,
                           int* __restrict__ rowPtrN, int G) {
    __shared__ int s[256];
    int t = threadIdx.x;
    s[t] = (t < G) ? blockSums[t] : 0;
    __syncthreads();
    for (int off = 1; off < 256; off <<= 1) {
        int v = (t >= off) ? s[t - off] : 0;
        __syncthreads();
        s[t] += v;
        __syncthreads();
    }
    if (t < G) blockOff[t] = (t > 0) ? s[t - 1] : 0;
    if (t == 255) *rowPtrN = s[255];
}

__global__ void scan_part3(const int* __restrict__ counts, const int* __restrict__ blockOff,
                           int* __restrict__ rowPtr, int* __restrict__ cursor,
                           float* __restrict__ dinv, int N) {
    __shared__ int s[256];
    int t = threadIdx.x;
    int i = blockIdx.x * 256 + t;
    int c = (i < N) ? counts[i] : 0;
    s[t] = c;
    __syncthreads();
    for (int off = 1; off < 256; off <<= 1) {
        int v = (t >= off) ? s[t - off] : 0;
        __syncthreads();
        s[t] += v;
        __syncthreads();
    }
    if (i < N) {
        int o = blockOff[blockIdx.x] + s[t] - c;     // exclusive prefix
        rowPtr[i] = o;
        cursor[i] = o;
        dinv[i] = rsqrtf((float)c + 1.0f);
    }
}

__global__ void scatter_kernel(const int* __restrict__ srcv, const int* __restrict__ dstv,
                               int* __restrict__ cursor, int* __restrict__ sortedSrc, int E) {
    int e = blockIdx.x * blockDim.x + threadIdx.x;
    if (e >= E) return;
    int p = atomicAdd(&cursor[dstv[e]], 1);
    sortedSrc[p] = srcv[e];
}

// ---------------- MFMA GEMM -------------------------------------------------
// C[N,F] = A[N,K](bf16) @ (Wth+Wtl)[K,F]. Epilogue: *dinv?[row] + bias?[col]; relu?;
// optional out2 = bf16(v * dinv2[row]). 64x64 tile, K chunks of 64, XOR-swizzled LDS.
template <int K>
__global__ __launch_bounds__(256)
void mfma_gemm(const bf16* __restrict__ A,
               const bf16* __restrict__ Wth, const bf16* __restrict__ Wtl,
               const float* __restrict__ bias, const float* __restrict__ dinv,
               void* __restrict__ out, const int* __restrict__ flags,
               int outmode, int relu, bf16* __restrict__ out2,
               const float* __restrict__ dinv2, int F, int N) {
    __shared__ uint4 lds4[1536];               // 24 KB = 1536 x 16B granules
    char* lds = (char*)lds4;
    const int tid = threadIdx.x;
    const int w = tid >> 6, lane = tid & 63;
    const int rowBase = blockIdx.y * 64;
    const int colBase = blockIdx.x * 64;

    f32x4 zero = {0.f, 0.f, 0.f, 0.f};
    f32x4 acc[4];
#pragma unroll
    for (int n = 0; n < 4; ++n) acc[n] = zero;

    const int arow = (w << 4) + (lane & 15);
    const int aswz = arow & 7;
    const int colL = lane & 15;

    for (int kc = 0; kc < K; kc += 64) {
#pragma unroll
        for (int i = 0; i < 6; ++i) {
            const int g = i * 256 + tid;
            char* dst = lds + ((i * 256 + (w << 6)) << 4);
            const bf16* src;
            if (g < 512) {
                int r = g >> 3, c = g & 7;
                int gr = rowBase + r; if (gr >= N) gr = N - 1;
                src = A + (size_t)gr * K + kc + ((c ^ (r & 7)) << 3);
            } else if (g < 1024) {
                int h = g - 512; int cl = h >> 3, c = h & 7;
                src = Wth + (size_t)(colBase + cl) * K + kc + ((c ^ (cl & 7)) << 3);
            } else {
                int h = g - 1024; int cl = h >> 3, c = h & 7;
                src = Wtl + (size_t)(colBase + cl) * K + kc + ((c ^ (cl & 7)) << 3);
            }
            __builtin_amdgcn_global_load_lds(
                (const __attribute__((address_space(1))) void*)src,
                (__attribute__((address_space(3))) void*)dst, 16, 0, 0);
        }
        __syncthreads();

        const char* aB = lds;
        const char* hB = lds + 8192;
        const char* lB = lds + 16384;
#pragma unroll
        for (int ks = 0; ks < 2; ++ks) {
            const int c = (ks << 2) + (lane >> 4);
            short8 a = *(const short8*)(aB + (((arow << 3) + (c ^ aswz)) << 4));
#pragma unroll
            for (int n = 0; n < 4; ++n) {
                const int col = (n << 4) + colL;
                const int s = ((col << 3) + (c ^ (col & 7))) << 4;
                short8 bh = *(const short8*)(hB + s);
                short8 bl = *(const short8*)(lB + s);
                acc[n] = __builtin_amdgcn_mfma_f32_16x16x32_bf16(a, bh, acc[n], 0, 0, 0);
                acc[n] = __builtin_amdgcn_mfma_f32_16x16x32_bf16(a, bl, acc[n], 0, 0, 0);
            }
        }
        __syncthreads();
    }

    // C/D layout: col = lane&15, row = (lane>>4)*4 + reg (m89/m91)
    const int m32 = outmode ? flags[0] : 0;
    const int r0 = rowBase + (w << 4) + ((lane >> 4) << 2);
#pragma unroll
    for (int n = 0; n < 4; ++n) {
        const int col = colBase + (n << 4) + colL;
        const float bv = bias ? bias[col] : 0.0f;
#pragma unroll
        for (int r = 0; r < 4; ++r) {
            const int row = r0 + r;
            if (row < N) {
                float v = acc[n][r];
                if (dinv) v *= dinv[row];
                v += bv;
                if (relu) v = fmaxf(v, 0.0f);
                size_t o = (size_t)row * F + col;
                if (m32) ((float*)out)[o] = v;
                else     ((bf16*)out)[o] = __float2bfloat16(v);
                if (out2) out2[o] = __float2bfloat16(v * dinv2[row]);
            }
        }
    }
}

// ---------------- gather: single pass, half-wave row pairing ----------------
// out[node,:] = act(dinv[node]*(Σ_in H'[s] + H'[node]) + bias).
// Lanes 0-31 process even entries, lanes 32-63 odd (per-lane shfl source);
// each lane covers F/32 columns via one wide load (uint for F=64, uint2 for
// F=128) so each half-wave reads a FULL row. Cross-half combine = 1 shfl_xor.
// Halves the serial shfl/addr chain vs 1-row-per-instruction; same bytes.
template <int F>
__global__ void gather_kernel(const bf16* __restrict__ Hs, const int* __restrict__ rowPtr,
                              const int* __restrict__ sortedSrc, const float* __restrict__ dinv,
                              const float* __restrict__ bias, bf16* __restrict__ out,
                              int relu, int N) {
    constexpr int CPL = F / 32;                  // cols per lane (2 or 4)
    int node = blockIdx.x * 4 + (threadIdx.x >> 6);
    int lane = threadIdx.x & 63;
    if (node >= N) return;
    const int half = lane >> 5;
    const int cl = lane & 31;
    const size_t cbase = (size_t)CPL * cl;
    float a0 = 0.0f, a1 = 0.0f, a2 = 0.0f, a3 = 0.0f;
    const int beg = rowPtr[node], end = rowPtr[node + 1];
    const int total = end - beg + 1;             // entry 0 = self
    for (int b0 = 0; b0 < total; b0 += 64) {
        int idx = b0 + lane;
        int myS = 0;
        if (idx == 0) myS = node;
        else if (idx < total) myS = sortedSrc[beg + idx - 1];
        int m = total - b0; if (m > 64) m = 64;
        int j = 0;
        for (; j + 3 < m; j += 4) {              // 4 rows in flight (2 per half)
            int s0 = __shfl(myS, j + half);
            int s1 = __shfl(myS, j + 2 + half);
            const bf16* r0 = Hs + (size_t)s0 * F + cbase;
            const bf16* r1 = Hs + (size_t)s1 * F + cbase;
            if constexpr (F == 64) {
                unsigned int u0 = *(const unsigned int*)r0;
                unsigned int u1 = *(const unsigned int*)r1;
                union { unsigned int i; float f; } lo, hi;
                lo.i = u0 << 16; hi.i = u0 & 0xffff0000u; a0 += lo.f; a1 += hi.f;
                lo.i = u1 << 16; hi.i = u1 & 0xffff0000u; a0 += lo.f; a1 += hi.f;
            } else {
                uint2 u0 = *(const uint2*)r0;
                uint2 u1 = *(const uint2*)r1;
                union { unsigned int i; float f; } c0, c1, c2, c3;
                c0.i = u0.x << 16; c1.i = u0.x & 0xffff0000u;
                c2.i = u0.y << 16; c3.i = u0.y & 0xffff0000u;
                a0 += c0.f; a1 += c1.f; a2 += c2.f; a3 += c3.f;
                c0.i = u1.x << 16; c1.i = u1.x & 0xffff0000u;
                c2.i = u1.y << 16; c3.i = u1.y & 0xffff0000u;
                a0 += c0.f; a1 += c1.f; a2 += c2.f; a3 += c3.f;
            }
        }
        for (; j < m; j += 2) {                  // tail: entry j+half (if valid)
            int idx2 = j + half;
            int s0 = __shfl(myS, idx2);
            if (idx2 < m) {
                const bf16* r0 = Hs + (size_t)s0 * F + cbase;
                if constexpr (F == 64) {
                    unsigned int u0 = *(const unsigned int*)r0;
                    union { unsigned int i; float f; } lo, hi;
                    lo.i = u0 << 16; hi.i = u0 & 0xffff0000u; a0 += lo.f; a1 += hi.f;
                } else {
                    uint2 u0 = *(const uint2*)r0;
                    union { unsigned int i; float f; } c0, c1, c2, c3;
                    c0.i = u0.x << 16; c1.i = u0.x & 0xffff0000u;
                    c2.i = u0.y << 16; c3.i = u0.y & 0xffff0000u;
                    a0 += c0.f; a1 += c1.f; a2 += c2.f; a3 += c3.f;
                }
            }
        }
    }
    a0 += __shfl_xor(a0, 32);
    a1 += __shfl_xor(a1, 32);
    if constexpr (F == 128) {
        a2 += __shfl_xor(a2, 32);
        a3 += __shfl_xor(a3, 32);
    }
    if (half == 0) {
        const float di = dinv[node];
        float v0 = a0 * di, v1 = a1 * di;
        if (bias) { v0 += bias[cbase]; v1 += bias[cbase + 1]; }
        if (relu) { v0 = fmaxf(v0, 0.0f); v1 = fmaxf(v1, 0.0f); }
        if constexpr (F == 64) {
            *(unsigned int*)(out + (size_t)node * F + cbase) = packbf2(v0, v1);
        } else {
            float v2 = a2 * di, v3 = a3 * di;
            if (bias) { v2 += bias[cbase + 2]; v3 += bias[cbase + 3]; }
            if (relu) { v2 = fmaxf(v2, 0.0f); v3 = fmaxf(v3, 0.0f); }
            uint2 p; p.x = packbf2(v0, v1); p.y = packbf2(v2, v3);
            *(uint2*)(out + (size_t)node * F + cbase) = p;
        }
    }
}

// ---------------- link predictor --------------------------------------------
__global__ void link_pre(const bf16* __restrict__ Z, const float* __restrict__ lw,
                         float* __restrict__ ab, int N) {
    int node = blockIdx.x * (blockDim.x >> 6) + (threadIdx.x >> 6);
    int lane = threadIdx.x & 63;
    if (node >= N) return;
    float zv = b2f(Z[(size_t)node * 64 + lane]);
    float va = zv * lw[lane];
    float vb = zv * lw[64 + lane];
#pragma unroll
    for (int off = 32; off > 0; off >>= 1) {
        va += __shfl_down(va, off);
        vb += __shfl_down(vb, off);
    }
    if (lane == 0) { ab[2 * node] = va; ab[2 * node + 1] = vb; }
}

__global__ void link_edge(const float* __restrict__ ab, const int* __restrict__ srcv,
                          const int* __restrict__ dstv, const float* __restrict__ lb,
                          void* __restrict__ out, const int* __restrict__ flags,
                          size_t outOff, int E) {
    int e = blockIdx.x * blockDim.x + threadIdx.x;
    if (e >= E) return;
    float v = ab[2 * srcv[e]] + ab[2 * dstv[e] + 1] + lb[0];
    float sv = 1.0f / (1.0f + expf(-v));
    if (flags[0]) ((float*)out)[outOff + e] = sv;
    else          ((bf16*)out)[outOff + e] = __float2bfloat16(sv);
}

// ---------------- launch ----------------------------------------------------
extern "C" void kernel_launch(void* const* d_in, const int* in_sizes, int n_in,
                              void* d_out, int out_size, void* d_ws, size_t ws_size,
                              hipStream_t stream) {
    const int N = in_sizes[0] / 128;   // 50000
    const int E = in_sizes[1] / 2;     // 800000

    char* base = (char*)d_ws;
    size_t off = 0;
    auto alloc = [&](size_t bytes) { char* p = base + off; off = (off + bytes + 255) & ~(size_t)255; return p; };
    int*   flags  = (int*)  alloc(256);
    float* dinv   = (float*)alloc((size_t)N * 4);
    float* Wc     = (float*)alloc((size_t)210689 * 4);
    int*   counts = (int*)  alloc((size_t)N * 4);
    int*   rowPtr = (int*)  alloc(((size_t)N + 1) * 4);
    int*   cursor = (int*)  alloc((size_t)N * 4);
    int*   sortedSrc = (int*)alloc((size_t)E * 4);
    int*   srcd   = (int*)  alloc((size_t)E * 4);
    int*   dstd   = (int*)  alloc((size_t)E * 4);
    bf16*  Hs     = (bf16*) alloc((size_t)N * 256 * 2);  // scaled GEMM out / agg buffer
    bf16*  P0     = (bf16*) alloc((size_t)N * 256 * 2);  // layer output
    bf16*  z      = (bf16*) alloc((size_t)N * 64 * 2);
    bf16*  zs     = (bf16*) alloc((size_t)N * 64 * 2);   // dinv ⊙ z
    bf16*  Wth    = (bf16*) alloc((size_t)208896 * 2);
    bf16*  Wtl    = (bf16*) alloc((size_t)208896 * 2);
    float* ab     = (float*)alloc((size_t)N * 2 * 4);
    int*   blockSums = (int*)alloc(256 * 4);
    int*   blockOff  = (int*)alloc(256 * 4);

    const int W_EB1 = 16384, W_EB2 = 24704, W_EFB = 28864, W_DB1 = 45312,
              W_DB2 = 78336, W_DFB = 209536, W_LW = 210560, W_LB = 210688;
    const int T_EW1 = 0, T_EW2 = 16384, T_EFW = 24576, T_DW1 = 28672,
              T_DW2 = 45056, T_DFW = 77824;

    det_kernel<<<1, 256, 0, stream>>>((const unsigned short*)d_in[0], (const int*)d_in[1], flags);

    // CSR + dinv (hist fused into edge canon; multi-block scan)
    hipMemsetAsync(counts, 0, (size_t)N * 4, stream);
    canon_edges_hist<<<(E + 255) / 256, 256, 0, stream>>>((const int*)d_in[1], flags,
                                                          srcd, dstd, counts, E);
    const int gScan = (N + 255) / 256;
    scan_part1<<<gScan, 256, 0, stream>>>(counts, blockSums, N);
    scan_part2<<<1, 256, 0, stream>>>(blockSums, blockOff, rowPtr + N, gScan);
    scan_part3<<<gScan, 256, 0, stream>>>(counts, blockOff, rowPtr, cursor, dinv, N);
    scatter_kernel<<<(E + 255) / 256, 256, 0, stream>>>(srcd, dstd, cursor, sortedSrc, E);

    {   // biases / link weights -> canonical fp32 (1 launch)
        CanonWB cb;
        const int idx[8]  = {3, 5, 7, 9, 11, 13, 14, 15};
        const int woff[8] = {W_EB1, W_EB2, W_EFB, W_DB1, W_DB2, W_DFB, W_LW, W_LB};
        for (int j = 0; j < 8; ++j) {
            cb.src[j] = d_in[idx[j]];
            cb.dst[j] = Wc + woff[j];
            cb.n[j] = in_sizes[idx[j]];
        }
        canon_w_batch<<<8, 256, 0, stream>>>(cb, flags);
    }
    {   // GEMM weights -> transposed bf16 hi/lo split (1 launch)
        PrepB pb;
        const int idx[6]  = {2, 4, 6, 8, 10, 12};
        const int toff[6] = {T_EW1, T_EW2, T_EFW, T_DW1, T_DW2, T_DFW};
        const int lgk[6]  = {7, 7, 6, 6, 8, 7};
        const int ff[6]   = {128, 64, 64, 256, 128, 1024};
        int total = 0;
        for (int j = 0; j < 6; ++j) {
            pb.src[j] = d_in[idx[j]];
            pb.lgK[j] = lgk[j];
            pb.F[j] = ff[j];
            pb.off[j] = toff[j];
            pb.end[j] = toff[j] + (ff[j] << lgk[j]);
            total = pb.end[j];
        }
        prep_wt_batch<<<(total + 255) / 256, 256, 0, stream>>>(pb, flags, Wth, Wtl, total);
    }
    canon_x8<<<(N * 16 + 255) / 256, 256, 0, stream>>>(d_in[0], flags, P0, N * 16);

    const int gRB = (N + 63) / 64;
    const int gG = (N + 3) / 4;

    // Encoder GCN1: 128 -> 128 (H' = dinv * X@W), ReLU in gather
    mfma_gemm<128><<<dim3(2, gRB), 256, 0, stream>>>(P0, Wth + T_EW1, Wtl + T_EW1,
                                                     nullptr, dinv, Hs, flags, 0, 0,
                                                     nullptr, nullptr, 128, N);
    gather_kernel<128><<<gG, 256, 0, stream>>>(Hs, rowPtr, sortedSrc, dinv, Wc + W_EB1, P0, 1, N);

    // Encoder GCN2: 128 -> 64
    mfma_gemm<128><<<dim3(1, gRB), 256, 0, stream>>>(P0, Wth + T_EW2, Wtl + T_EW2,
                                                     nullptr, dinv, Hs, flags, 0, 0,
                                                     nullptr, nullptr, 64, N);
    gather_kernel<64><<<gG, 256, 0, stream>>>(Hs, rowPtr, sortedSrc, dinv, Wc + W_EB2, P0, 0, N);

    // Latent fc: z = P0 @ efw + efb; zs = dinv ⊙ z (free in epilogue)
    mfma_gemm<64><<<dim3(1, gRB), 256, 0, stream>>>(P0, Wth + T_EFW, Wtl + T_EFW,
                                                    Wc + W_EFB, nullptr, z, flags, 0, 0,
                                                    zs, dinv, 64, N);

    // link partials (needs z only)
    link_pre<<<gG, 256, 0, stream>>>(z, Wc + W_LW, ab, N);

    // Decoder GCN1 (aggregate-before-transform on F=64), then GEMM 64->256 +bias+ReLU
    gather_kernel<64><<<gG, 256, 0, stream>>>(zs, rowPtr, sortedSrc, dinv, nullptr, Hs, 0, N);
    mfma_gemm<64><<<dim3(4, gRB), 256, 0, stream>>>(Hs, Wth + T_DW1, Wtl + T_DW1,
                                                    Wc + W_DB1, nullptr, P0, flags, 0, 1,
                                                    nullptr, nullptr, 256, N);

    // Decoder GCN2: 256 -> 128
    mfma_gemm<256><<<dim3(2, gRB), 256, 0, stream>>>(P0, Wth + T_DW2, Wtl + T_DW2,
                                                     nullptr, dinv, Hs, flags, 0, 0,
                                                     nullptr, nullptr, 128, N);
    gather_kernel<128><<<gG, 256, 0, stream>>>(Hs, rowPtr, sortedSrc, dinv, Wc + W_DB2, P0, 0, N);

    // x_hat = P0 @ dfw + dfb (128 -> 1024) into d_out, detected dtype
    mfma_gemm<128><<<dim3(16, gRB), 256, 0, stream>>>(P0, Wth + T_DFW, Wtl + T_DFW,
                                                      Wc + W_DFB, nullptr, d_out, flags, 1, 0,
                                                      nullptr, nullptr, 1024, N);

    // edge_probs
    link_edge<<<(E + 255) / 256, 256, 0, stream>>>(ab, srcd, dstd, Wc + W_LB,
                                                   d_out, flags, (size_t)N * 1024, E);
}